// Round 17
// baseline (239.231 us; speedup 1.0000x reference)
//
#include <hip/hip_runtime.h>
#include <hip/hip_bf16.h>

typedef __hip_bfloat16 bf16;
typedef __attribute__((ext_vector_type(8))) short short8;
typedef __attribute__((ext_vector_type(16))) float floatx16;

__device__ __forceinline__ float tof(bf16 x){ return __bfloat162float(x); }
__device__ __forceinline__ float bflo(unsigned u){ return __uint_as_float(u<<16); }
__device__ __forceinline__ float bfhi(unsigned u){ return __uint_as_float(u & 0xFFFF0000u); }
__device__ __forceinline__ float ldT(const void* p, long i, bool isf){
  return isf ? ((const float*)p)[i] : tof(((const bf16*)p)[i]);
}
__device__ __forceinline__ void stT(void* p, long i, bool isf, float v){
  if (isf) ((float*)p)[i] = v; else ((bf16*)p)[i] = __float2bfloat16(v);
}

#define LL 64
#define DD 144
#define NN 4096
#define HH 8
#define HDIM 18
#define SCALE 0.23570226039551584f
#define LOG2E 1.4426950408889634f

// ---- one-shot weight prep (also publishes dtype flag) ----
__global__ __launch_bounds__(256) void prep_weights(const unsigned* __restrict__ smaskw,
    int* __restrict__ dflag,
    const void* __restrict__ wqkv, const void* __restrict__ wg,
    const void* __restrict__ wout, const void* __restrict__ w1, const void* __restrict__ w2,
    const void* __restrict__ swq, const void* __restrict__ swkv,
    const void* __restrict__ swout, const void* __restrict__ sw1, const void* __restrict__ sw2,
    bf16* __restrict__ F1, bf16* __restrict__ Fout, bf16* __restrict__ Fw1,
    bf16* __restrict__ Fw2, bf16* __restrict__ Fs1, bf16* __restrict__ Wtswout,
    bf16* __restrict__ Wtst1, bf16* __restrict__ Wtst2){
  bool isf = (smaskw[0] == 0x3F800000u);
  if (blockIdx.x==0 && threadIdx.x==0) dflag[0] = isf ? 4 : 2;
  long t = (long)blockIdx.x*256 + threadIdx.x;
  if (t < 82944){
    int j=t&7, lane=(int)((t>>3)&63); long tk=t>>9; int ks=tk%9, tile=tk/9;
    int col=tile*32+(lane&31); int k=ks*16+(lane>>5)*8+j;
    float v = (col<432)? ldT(wqkv,(long)k*432+col,isf) : ldT(wg,(long)k*144+(col-432),isf);
    F1[t]=__float2bfloat16(v); return;
  } t -= 82944;
  if (t < 23040){
    int j=t&7, lane=(int)((t>>3)&63); long tk=t>>9; int ks=tk%9, tile=tk/9;
    int col=tile*32+(lane&31); if (col>143) col=143;
    int k=ks*16+(lane>>5)*8+j;
    Fout[t]=__float2bfloat16(ldT(wout,(long)k*144+col,isf)); return;
  } t -= 23040;
  if (t < 82944){
    int j=t&7, lane=(int)((t>>3)&63); long tk=t>>9; int ks=tk%9, tile=tk/9;
    int col=tile*32+(lane&31); int k=ks*16+(lane>>5)*8+j;
    Fw1[t]=__float2bfloat16(ldT(w1,(long)k*576+col,isf)); return;
  } t -= 82944;
  if (t < 92160){
    int j=t&7, lane=(int)((t>>3)&63); long tk=t>>9; int ks=tk%36, tile=tk/36;
    int col=tile*32+(lane&31); if (col>143) col=143;
    int k=ks*16+(lane>>5)*8+j;
    Fw2[t]=__float2bfloat16(ldT(w2,(long)k*144+col,isf)); return;
  } t -= 92160;
  if (t < 64512){
    int j=t&7, lane=(int)((t>>3)&63); long tk=t>>9; int ks=tk%9, tile=tk/9;
    int col=tile*32+(lane&31); if (col>431) col=431;
    int k=ks*16+(lane>>5)*8+j;
    float v = (col<144)? ldT(swq,(long)k*144+col,isf) : ldT(swkv,(long)k*288+(col-144),isf);
    Fs1[t]=__float2bfloat16(v); return;
  } t -= 64512;
  if (t < 20736){ int c=t/144,k=t-(long)c*144; Wtswout[t]=__float2bfloat16(ldT(swout,(long)k*144+c,isf)); return; }
  t -= 20736;
  if (t < 82944){ int c=t/144,k=t-(long)c*144; Wtst1[t]=__float2bfloat16(ldT(sw1,(long)k*576+c,isf)); return; }
  t -= 82944;
  if (t < 82944){ int c=t/576,k=t-(long)c*576; Wtst2[t]=__float2bfloat16(ldT(sw2,(long)k*144+c,isf)); return; }
}

// ---- LayerNorm rows -> bf16. 4 rows/block ----
__global__ __launch_bounds__(256) void ln_rows(const int* __restrict__ df,
    const void* __restrict__ xv,
    const void* __restrict__ gv, const void* __restrict__ bv,
    bf16* __restrict__ out){
  bool isf = (df[0]==4);
  int row = blockIdx.x*4 + (threadIdx.x>>6);
  int lane = threadIdx.x & 63;
  long base = (long)row*DD;
  float e0 = ldT(xv,base+lane,isf);
  float e1 = ldT(xv,base+lane+64,isf);
  float e2 = (lane<16) ? ldT(xv,base+lane+128,isf) : 0.f;
  float s = e0+e1+e2;
  #pragma unroll
  for (int o=32;o;o>>=1) s += __shfl_xor(s,o);
  float mean = s*(1.f/144.f);
  float d0=e0-mean, d1=e1-mean, d2=(lane<16)?(e2-mean):0.f;
  float v = d0*d0+d1*d1+d2*d2;
  #pragma unroll
  for (int o=32;o;o>>=1) v += __shfl_xor(v,o);
  float rstd = rsqrtf(v*(1.f/144.f)+1e-5f);
  out[base+lane]    = __float2bfloat16(d0*rstd*ldT(gv,lane,isf)    + ldT(bv,lane,isf));
  out[base+lane+64] = __float2bfloat16(d1*rstd*ldT(gv,lane+64,isf) + ldT(bv,lane+64,isf));
  if (lane<16)
    out[base+lane+128] = __float2bfloat16(d2*rstd*ldT(gv,lane+128,isf) + ldT(bv,lane+128,isf));
}

// ---- fused z @ [wqkv|wg] with frag weights. grid (9,64) ----
__global__ __launch_bounds__(256) void gemm_fused1(const int* __restrict__ df,
    const bf16* __restrict__ z, const bf16* __restrict__ F1,
    const void* __restrict__ pmask,
    bf16* __restrict__ Qb, bf16* __restrict__ Kf, bf16* __restrict__ Vf,
    bf16* __restrict__ gbuf){
  __shared__ short As[64*152];
  bool isf = df[0]==4;
  int row0 = blockIdx.y*64, col0 = blockIdx.x*64;
  int tid=threadIdx.x, lane=tid&63, l31=lane&31, w=tid>>6, wr=w>>1, wc=w&1;
  int g=(lane>>5)*8;
  for (int t=tid; t<64*72; t+=256){
    int m = t/72, dw = t%72;
    ((unsigned*)As)[m*76+dw] = ((const unsigned*)(z + (size_t)(row0+m)*144))[dw];
  }
  __syncthreads();
  int tile = blockIdx.x*2 + wc;
  const short8* wf = (const short8*)F1;
  floatx16 acc;
  #pragma unroll
  for (int i=0;i<16;i++) acc[i]=0.f;
  #pragma unroll
  for (int ks=0; ks<9; ks++){
    short8 af = *(const short8*)&As[(l31+32*wr)*152 + ks*16 + g];
    acc = __builtin_amdgcn_mfma_f32_32x32x16_bf16(af, wf[(tile*9+ks)*64+lane], acc, 0,0,0);
  }
  int col = col0 + wc*32 + l31;
  #pragma unroll
  for (int r=0;r<16;r++){
    int row = row0 + 32*wr + (r&3)+8*(r>>2)+4*(lane>>5);
    if (col < 144){
      int hh = col/18, d = col - hh*18;
      Qb[((size_t)hh*NN+row)*32 + d] = __float2bfloat16(acc[r]*(SCALE*LOG2E));
    } else if (col < 288){
      int c2 = col-144, hh = c2/18, d = c2 - hh*18;
      int f = d>>4, rem = d&15, gs = rem>>3, j = rem&7;
      Kf[((((size_t)hh*128 + (row>>5))*2 + f)*64 + gs*32 + (row&31))*8 + j]
        = __float2bfloat16(acc[r]);
    } else if (col < 432){
      int c2 = col-288, hh = c2/18, d = c2 - hh*18;
      float pm = (ldT(pmask,row,isf)>0.f)?1.f:0.f;
      int kin = row&31, f = kin>>4, k15 = kin&15;
      int gs = (k15>>2)&1, j = (k15&3) | (((k15>>3)&1)<<2);
      Vf[((((size_t)hh*128 + (row>>5))*2 + f)*64 + gs*32 + d)*8 + j]
        = __float2bfloat16(acc[r]*pm);
    } else {
      int c2 = col-432;
      float gt = 1.f/(1.f+__expf(fminf(-acc[r],30.f)));
      gbuf[(size_t)row*DD+c2] = __float2bfloat16(gt);
    }
  }
  if (blockIdx.x==0){
    for (int t=threadIdx.x; t<64*8*7; t+=256){
      int n = row0 + t/56; int rem = t%56; int hh = rem/7, dw = rem%7 + 9;
      ((unsigned*)(Qb + ((size_t)hh*NN+n)*32))[dw] = 0;
    }
    for (int t=threadIdx.x; t<64*8; t+=256){
      int n = row0 + (t>>3), hh = t&7;
      float pm = (ldT(pmask,n,isf)>0.f)?1.f:0.f;
      int kin = n&31, f = kin>>4, k15 = kin&15;
      int gs = (k15>>2)&1, j = (k15&3) | (((k15>>3)&1)<<2);
      Vf[((((size_t)hh*128 + (n>>5))*2 + f)*64 + gs*32 + 18)*8 + j] = __float2bfloat16(pm);
    }
  }
}

// ---- pair attention v6: key-split x2, raw (num,den) partials. grid 2048 ----
// bx: h = bx>>8, rem=bx&255, qt=rem>>1, kspl=rem&1. Wave strip = kspl*2048 + w*512 (16 chunks).
// part layout: [(kspl*8+h)][n][20] f32
__global__ __launch_bounds__(256) void pair_attn_mfma(const int* __restrict__ df,
    const bf16* __restrict__ Qb, const bf16* __restrict__ Kf,
    const bf16* __restrict__ Vf, float* __restrict__ part){
  __shared__ float Comb[4][32][20];
  int bx = blockIdx.x;
  int h = bx >> 8, rem = bx & 255, qt = rem >> 1, kspl = rem & 1;
  int tid = threadIdx.x;
  int w = tid >> 6, lane = tid & 63;
  int l31 = lane & 31, gsel = lane>>5;

  const unsigned* qp = (const unsigned*)(Qb + ((size_t)h*NN + qt*32 + l31)*32);
  short8 qf0, qf1;
  #pragma unroll
  for (int j=0;j<4;j++) ((unsigned*)&qf0)[j] = qp[gsel*4+j];
  #pragma unroll
  for (int j=0;j<4;j++) ((unsigned*)&qf1)[j] = qp[8+gsel*4+j];

  floatx16 o;
  #pragma unroll
  for (int i=0;i<16;i++) o[i]=0.f;

  const short8* kf8 = (const short8*)Kf + (size_t)h*16384;
  const short8* vf8 = (const short8*)Vf + (size_t)h*16384;
  int c0 = kspl*64 + w*16;        // chunk index base (each chunk = 32 keys)

  short8 af0 = kf8[(c0*2+0)*64 + lane];
  short8 af1 = kf8[(c0*2+1)*64 + lane];
  short8 av0 = vf8[(c0*2+0)*64 + lane];
  short8 av1 = vf8[(c0*2+1)*64 + lane];

  for (int cc=0; cc<16; cc++){
    int cn = c0 + (cc<15 ? cc+1 : 15);
    short8 naf0 = kf8[(cn*2+0)*64 + lane];
    short8 naf1 = kf8[(cn*2+1)*64 + lane];
    short8 nav0 = vf8[(cn*2+0)*64 + lane];
    short8 nav1 = vf8[(cn*2+1)*64 + lane];

    floatx16 s;
    #pragma unroll
    for (int i=0;i<16;i++) s[i]=0.f;
    s = __builtin_amdgcn_mfma_f32_32x32x16_bf16(af0, qf0, s, 0,0,0);
    s = __builtin_amdgcn_mfma_f32_32x32x16_bf16(af1, qf1, s, 0,0,0);

    short8 P1, P2;
    #pragma unroll
    for (int j=0;j<4;j++){
      unsigned e0 = __float_as_uint(__builtin_amdgcn_exp2f(s[2*j]));
      unsigned e1 = __float_as_uint(__builtin_amdgcn_exp2f(s[2*j+1]));
      ((unsigned*)&P1)[j] = (e0>>16) | (e1 & 0xFFFF0000u);
      unsigned e2 = __float_as_uint(__builtin_amdgcn_exp2f(s[8+2*j]));
      unsigned e3 = __float_as_uint(__builtin_amdgcn_exp2f(s[9+2*j]));
      ((unsigned*)&P2)[j] = (e2>>16) | (e3 & 0xFFFF0000u);
    }

    o = __builtin_amdgcn_mfma_f32_32x32x16_bf16(av0, P1, o, 0,0,0);
    o = __builtin_amdgcn_mfma_f32_32x32x16_bf16(av1, P2, o, 0,0,0);

    af0=naf0; af1=naf1; av0=nav0; av1=nav1;
  }

  #pragma unroll
  for (int r=0;r<16;r++){
    int d = (r&3) + 8*(r>>2) + 4*gsel;
    if (d < 20) Comb[w][l31][d] = o[r];
  }
  __syncthreads();
  float* pb = part + ((size_t)(kspl*8+h)*NN + qt*32)*20;
  for (int t=tid; t<32*20; t+=256){
    int q = t/20, d = t-q*20;
    pb[q*20+d] = Comb[0][q][d]+Comb[1][q][d]+Comb[2][q][d]+Comb[3][q][d];
  }
}

// ---- pair tail v6: 512 blocks x 8 rows, 512 threads; combines attention partials ----
__global__ __launch_bounds__(512) void pair_tail(const int* __restrict__ df,
    const float* __restrict__ part, const bf16* __restrict__ gbuf,
    const void* __restrict__ pairv, const void* __restrict__ pmaskv,
    const bf16* __restrict__ Fout, const void* __restrict__ ptln_g, const void* __restrict__ ptln_b,
    const bf16* __restrict__ Fw1, const void* __restrict__ b1v,
    const bf16* __restrict__ Fw2, const void* __restrict__ b2v,
    const void* __restrict__ wb, void* __restrict__ outP, long outOff,
    float* __restrict__ biasb){
  __shared__ __align__(16) char smem[16384];
  float* p1  = (float*)smem;
  short* ts  = (short*)(smem + 4608);
  short* hh_ = (short*)(smem + 7040);
  float* outv = (float*)(smem + 7040);

  bool isf = df[0]==4;
  int tid=threadIdx.x, lane=tid&63, l31=lane&31, gsel=lane>>5, g=gsel*8;
  int w=tid>>6;
  int lrow = l31 & 7;
  int r0 = blockIdx.x*8;
  const short8* foutf = (const short8*)Fout;
  const short8* fw1f  = (const short8*)Fw1;
  const short8* fw2f  = (const short8*)Fw2;

  // stage ao rows from partials: combine split 0/1, normalize
  for (int t=tid; t<8*144; t+=512){
    int m=t/144, col=t-m*144;
    int hh=col/18, d=col-hh*18;
    long n = r0 + m;
    const float* p0 = part + ((size_t)hh*NN + n)*20;
    const float* p1v = part + ((size_t)(8+hh)*NN + n)*20;
    float num = p0[d] + p1v[d];
    float den = fmaxf(p0[18] + p1v[18], 1e-20f);
    bf16 v = __float2bfloat16(num/den);
    ts[m*152+col] = *reinterpret_cast<short*>(&v);
  }
  __syncthreads();

  // phase A: wout (5 tiles, KS=9)
  for (int tile=w; tile<5; tile+=8){
    int c0=tile*32;
    floatx16 acc;
    #pragma unroll
    for (int i=0;i<16;i++) acc[i]=0.f;
    #pragma unroll
    for (int ks=0; ks<9; ks++){
      short8 af = *(const short8*)&ts[lrow*152 + ks*16 + g];
      acc = __builtin_amdgcn_mfma_f32_32x32x16_bf16(af, foutf[(tile*9+ks)*64+lane], acc, 0,0,0);
    }
    if (c0+l31 < 144){
      #pragma unroll
      for (int r=0;r<16;r++){
        int row=(r&3)+8*(r>>2)+4*gsel;
        if (row<8) p1[row*144 + c0+l31] = acc[r];
      }
    }
  }
  __syncthreads();
  for (int t=tid; t<8*144; t+=512){
    int row=t/144; int col=t-row*144;
    long gidx=(long)(r0+row)*144 + col;
    float pm = (ldT(pmaskv, r0+row, isf)>0.f)?1.f:0.f;
    p1[t] = ldT(pairv,gidx,isf) + p1[t]*tof(gbuf[gidx])*pm;
  }
  __syncthreads();
  if (w < 8){
    int rr = w;
    float e0=p1[rr*144+lane], e1=p1[rr*144+lane+64], e2=(lane<16)?p1[rr*144+lane+128]:0.f;
    float s=e0+e1+e2;
    #pragma unroll
    for (int o=32;o;o>>=1) s += __shfl_xor(s,o);
    float mean=s*(1.f/144.f);
    float d0=e0-mean, d1=e1-mean, d2=(lane<16)?(e2-mean):0.f;
    float v=d0*d0+d1*d1+d2*d2;
    #pragma unroll
    for (int o=32;o;o>>=1) v += __shfl_xor(v,o);
    float rstd=rsqrtf(v*(1.f/144.f)+1e-5f);
    bf16 h0 = __float2bfloat16(d0*rstd*ldT(ptln_g,lane,isf)    + ldT(ptln_b,lane,isf));
    bf16 h1 = __float2bfloat16(d1*rstd*ldT(ptln_g,lane+64,isf) + ldT(ptln_b,lane+64,isf));
    ts[rr*152+lane]    = *reinterpret_cast<short*>(&h0);
    ts[rr*152+lane+64] = *reinterpret_cast<short*>(&h1);
    if (lane<16){
      bf16 h2 = __float2bfloat16(d2*rstd*ldT(ptln_g,lane+128,isf) + ldT(ptln_b,lane+128,isf));
      ts[rr*152+lane+128] = *reinterpret_cast<short*>(&h2);
    }
  }
  __syncthreads();
  // phase C: w1 (18 tiles, KS=9)
  for (int tile=w; tile<18; tile+=8){
    int c0=tile*32, colB=c0+l31;
    floatx16 acc;
    #pragma unroll
    for (int i=0;i<16;i++) acc[i]=0.f;
    #pragma unroll
    for (int ks=0; ks<9; ks++){
      short8 af = *(const short8*)&ts[lrow*152 + ks*16 + g];
      acc = __builtin_amdgcn_mfma_f32_32x32x16_bf16(af, fw1f[(tile*9+ks)*64+lane], acc, 0,0,0);
    }
    float bb = ldT(b1v,colB,isf);
    #pragma unroll
    for (int r=0;r<16;r++){
      int row=(r&3)+8*(r>>2)+4*gsel;
      if (row<8){
        bf16 hv = __float2bfloat16(fmaxf(acc[r]+bb,0.f));
        hh_[row*584 + colB] = *reinterpret_cast<short*>(&hv);
      }
    }
  }
  __syncthreads();
  // phase D: w2 (5 tiles, KS=36)
  floatx16 fin; int fc0 = -1;
  for (int tile=w; tile<5; tile+=8){
    int c0=tile*32;
    int colB=c0+l31; if (colB>143) colB=143;
    floatx16 acc;
    #pragma unroll
    for (int i=0;i<16;i++) acc[i]=0.f;
    #pragma unroll
    for (int ks=0; ks<36; ks++){
      short8 af = *(const short8*)&hh_[lrow*584 + ks*16 + g];
      acc = __builtin_amdgcn_mfma_f32_32x32x16_bf16(af, fw2f[(tile*36+ks)*64+lane], acc, 0,0,0);
    }
    float bb = ldT(b2v,colB,isf);
    #pragma unroll
    for (int r=0;r<16;r++){
      int row=(r&3)+8*(r>>2)+4*gsel;
      float val = 0.f;
      if (row<8){
        float pm = (ldT(pmaskv, r0+row, isf)>0.f)?1.f:0.f;
        val = p1[row*144 + colB] + (acc[r]+bb)*pm;
        if (c0+l31 < 144)
          stT(outP, outOff + (long)(r0+row)*144 + c0+l31, isf, val);
      }
      fin[r]=val;
    }
    fc0 = c0;
  }
  __syncthreads();
  if (fc0 >= 0 && fc0+l31 < 144){
    #pragma unroll
    for (int r=0;r<16;r++){
      int row=(r&3)+8*(r>>2)+4*gsel;
      if (row<8) outv[row*144 + fc0+l31] = fin[r];
    }
  }
  __syncthreads();
  {
    int n = tid>>3, hb = tid&7;
    if (n < 8){
      float acc=0.f;
      #pragma unroll 4
      for (int k=0;k<144;k++) acc += outv[n*144+k]*ldT(wb,k*8+hb,isf);
      biasb[(size_t)(r0+n)*8+hb]=acc;
    }
  }
}

// ---- fused LN(single) + zs @ [wq|wkv] with frag weights. grid (7,1) ----
__global__ __launch_bounds__(256) void gemm_s1(const int* __restrict__ df,
    const void* __restrict__ single, const void* __restrict__ g, const void* __restrict__ b,
    const bf16* __restrict__ Fs1,
    bf16* __restrict__ q_sb, bf16* __restrict__ kv_sb){
  __shared__ short As[64*152];
  bool isf = df[0]==4;
  int tid=threadIdx.x, lane=tid&63, l31=lane&31, w=tid>>6, wr=w>>1, wc=w&1;
  int gg=(lane>>5)*8;
  for (int rr=w; rr<64; rr+=4){
    long base=(long)rr*DD;
    float e0=ldT(single,base+lane,isf), e1=ldT(single,base+lane+64,isf);
    float e2=(lane<16)?ldT(single,base+lane+128,isf):0.f;
    float s=e0+e1+e2;
    #pragma unroll
    for (int o=32;o;o>>=1) s += __shfl_xor(s,o);
    float mean=s*(1.f/144.f);
    float d0=e0-mean, d1=e1-mean, d2=(lane<16)?(e2-mean):0.f;
    float v=d0*d0+d1*d1+d2*d2;
    #pragma unroll
    for (int o=32;o;o>>=1) v += __shfl_xor(v,o);
    float rstd=rsqrtf(v*(1.f/144.f)+1e-5f);
    bf16 h0=__float2bfloat16(d0*rstd*ldT(g,lane,isf)+ldT(b,lane,isf));
    bf16 h1=__float2bfloat16(d1*rstd*ldT(g,lane+64,isf)+ldT(b,lane+64,isf));
    As[rr*152+lane]=*reinterpret_cast<short*>(&h0);
    As[rr*152+lane+64]=*reinterpret_cast<short*>(&h1);
    if (lane<16){
      bf16 h2=__float2bfloat16(d2*rstd*ldT(g,lane+128,isf)+ldT(b,lane+128,isf));
      As[rr*152+lane+128]=*reinterpret_cast<short*>(&h2);
    }
  }
  __syncthreads();
  int tile = blockIdx.x*2 + wc;
  const short8* wf = (const short8*)Fs1;
  floatx16 acc;
  #pragma unroll
  for (int i=0;i<16;i++) acc[i]=0.f;
  #pragma unroll
  for (int ks=0; ks<9; ks++){
    short8 af = *(const short8*)&As[(l31+32*wr)*152 + ks*16 + gg];
    acc = __builtin_amdgcn_mfma_f32_32x32x16_bf16(af, wf[(tile*9+ks)*64+lane], acc, 0,0,0);
  }
  int col = tile*32 + l31;
  if (col < 432){
    #pragma unroll
    for (int r=0;r<16;r++){
      int row = 32*wr + (r&3)+8*(r>>2)+4*(lane>>5);
      if (col<144) q_sb[(size_t)row*DD+col] = __float2bfloat16(acc[r]);
      else kv_sb[(size_t)row*288+(col-144)] = __float2bfloat16(acc[r]);
    }
  }
}

__device__ __forceinline__ void block_ln_stats(const float* xs, float* mr){
  int tid = threadIdx.x;
  if (tid < 64){
    float e0 = xs[tid], e1 = xs[tid+64], e2 = (tid<16)?xs[tid+128]:0.f;
    float s = e0+e1+e2;
    #pragma unroll
    for (int o=32;o;o>>=1) s += __shfl_xor(s,o);
    float mean = s*(1.f/144.f);
    float d0=e0-mean, d1=e1-mean, d2=(tid<16)?(e2-mean):0.f;
    float v = d0*d0+d1*d1+d2*d2;
    #pragma unroll
    for (int o=32;o;o>>=1) v += __shfl_xor(v,o);
    if (tid==0){ mr[0]=mean; mr[1]=rsqrtf(v*(1.f/144.f)+1e-5f); }
  }
  __syncthreads();
}

// ---- single attention ----
__global__ __launch_bounds__(64) void single_attn(const int* __restrict__ df,
    const bf16* __restrict__ qb, const bf16* __restrict__ kvb,
    const float* __restrict__ biasb, const void* __restrict__ smask,
    bf16* __restrict__ outb){
  bool isf = df[0]==4;
  int b = blockIdx.x; int h = b>>6; int i = b&63; int j = threadIdx.x;
  __shared__ float qs[HDIM];
  __shared__ float p[64];
  if (j<HDIM) qs[j] = tof(qb[i*DD + h*HDIM + j]);
  __syncthreads();
  const bf16* kr = kvb + j*288 + h*HDIM;
  float s=0.f;
  #pragma unroll
  for (int d=0;d<HDIM;d++) s += qs[d]*tof(kr[d]);
  s = fminf(s*SCALE + biasb[(i*64+j)*8 + h], 30.f);
  float e = (ldT(smask,j,isf)>0.f) ? __expf(s) : 0.f;
  p[j]=e;
  float tot=e;
  #pragma unroll
  for (int o=32;o;o>>=1) tot += __shfl_xor(tot,o);
  tot = fmaxf(tot, 1e-20f);
  __syncthreads();
  if (j<HDIM){
    float acc=0.f;
    for (int jj=0;jj<64;jj++) acc += p[jj]*tof(kvb[jj*288 + 144 + h*HDIM + j]);
    outb[i*DD + h*HDIM + j] = __float2bfloat16(acc/tot);
  }
}

// ---- fused single tail ----
__global__ __launch_bounds__(256) void single_tail(const int* __restrict__ df,
    const void* __restrict__ single, const bf16* __restrict__ ao,
    const void* __restrict__ smask, const bf16* __restrict__ Wtswout,
    const void* __restrict__ stln_g, const void* __restrict__ stln_b,
    const bf16* __restrict__ Wtst1, const void* __restrict__ st_b1,
    const bf16* __restrict__ Wtst2, const void* __restrict__ st_b2,
    void* __restrict__ outS){
  bool isf = df[0]==4;
  __shared__ float as_[DD], s1[DD], ts[DD], hs[576], mr[2];
  int n = blockIdx.x, tid = threadIdx.x;
  if (tid<DD) as_[tid] = tof(ao[n*DD+tid]);
  __syncthreads();
  float sm = ldT(smask,n,isf);
  if (tid<DD){
    const unsigned* wr = (const unsigned*)(Wtswout + (size_t)tid*DD);
    float a=0.f;
    #pragma unroll 4
    for (int kw=0; kw<72; kw++){ unsigned u = wr[kw]; a += as_[2*kw]*bflo(u) + as_[2*kw+1]*bfhi(u); }
    s1[tid] = ldT(single,(long)n*DD+tid,isf) + a*sm;
  }
  __syncthreads();
  block_ln_stats(s1, mr);
  if (tid<DD) ts[tid] = (s1[tid]-mr[0])*mr[1]*ldT(stln_g,tid,isf) + ldT(stln_b,tid,isf);
  __syncthreads();
  for (int c=tid;c<576;c+=256){
    const unsigned* wr = (const unsigned*)(Wtst1 + (size_t)c*DD);
    float a=ldT(st_b1,c,isf);
    #pragma unroll 4
    for (int kw=0; kw<72; kw++){ unsigned u = wr[kw]; a += ts[2*kw]*bflo(u) + ts[2*kw+1]*bfhi(u); }
    hs[c]=fmaxf(a,0.f);
  }
  __syncthreads();
  if (tid<DD){
    const unsigned* wr = (const unsigned*)(Wtst2 + (size_t)tid*576);
    float a=ldT(st_b2,tid,isf);
    #pragma unroll 4
    for (int kw=0; kw<288; kw++){ unsigned u = wr[kw]; a += hs[2*kw]*bflo(u) + hs[2*kw+1]*bfhi(u); }
    stT(outS,(long)n*DD+tid,isf, s1[tid] + a*sm);
  }
}

extern "C" void kernel_launch(void* const* d_in, const int* in_sizes, int n_in,
                              void* d_out, int out_size, void* d_ws, size_t ws_size,
                              hipStream_t stream) {
  char* wsb = (char*)d_ws;
  int*   dflag = (int*)wsb;
  bf16*  F1     = (bf16*)(wsb + 16);
  bf16*  Fout   = F1 + 82944;
  bf16*  Fw1    = Fout + 23040;
  bf16*  Fw2    = Fw1 + 82944;
  bf16*  Fs1    = Fw2 + 92160;
  bf16*  Wtswout= Fs1 + 64512;
  bf16*  Wtst1  = Wtswout + 20736;
  bf16*  Wtst2  = Wtst1 + 82944;
  bf16*  Qb   = Wtst2 + 82944;
  bf16*  Kf   = Qb + (size_t)HH*NN*32;
  bf16*  Vf   = Kf + (size_t)HH*131072;
  bf16*  gbuf = Vf + (size_t)HH*131072;
  bf16*  z    = gbuf + (size_t)NN*DD;
  float* part = (float*)(z + (size_t)NN*DD);        // 16*4096*20 f32 = 5.24 MB
  float* biasb= part + (size_t)16*NN*20;
  bf16*  q_sb = (bf16*)(biasb + NN*8);
  bf16*  kv_sb= q_sb + LL*DD;
  bf16*  ao_sb= kv_sb + LL*288;

  const long OUTP_OFF = (long)LL*DD;

  prep_weights<<<2079,256,0,stream>>>((const unsigned*)d_in[2], dflag,
      d_in[6], d_in[7], d_in[8], d_in[11], d_in[13],
      d_in[17], d_in[18], d_in[20], d_in[23], d_in[25],
      F1, Fout, Fw1, Fw2, Fs1, Wtswout, Wtst1, Wtst2);

  // ---- pair path ----
  ln_rows<<<NN/4,256,0,stream>>>(dflag, d_in[1], d_in[4], d_in[5], z);
  gemm_fused1<<<dim3(9,64),256,0,stream>>>(dflag, z, F1, d_in[3], Qb, Kf, Vf, gbuf);
  pair_attn_mfma<<<2048,256,0,stream>>>(dflag, Qb, Kf, Vf, part);
  pair_tail<<<512,512,0,stream>>>(dflag, part, gbuf, d_in[1], d_in[3],
                                  Fout, d_in[9], d_in[10], Fw1, d_in[12],
                                  Fw2, d_in[14], d_in[19], d_out, OUTP_OFF, biasb);

  // ---- single path ----
  gemm_s1<<<dim3(7,1),256,0,stream>>>(dflag, d_in[0], d_in[15], d_in[16], Fs1, q_sb, kv_sb);
  single_attn<<<HH*LL,64,0,stream>>>(dflag, q_sb, kv_sb, biasb, d_in[2], ao_sb);
  single_tail<<<LL,256,0,stream>>>(dflag, d_in[0], ao_sb, d_in[2], Wtswout,
                                   d_in[21], d_in[22], Wtst1, d_in[24], Wtst2, d_in[26],
                                   d_out);
  (void)in_sizes; (void)n_in; (void)out_size; (void)ws_size;
}

// Round 18
// 237.160 us; speedup vs baseline: 1.0087x; 1.0087x over previous
//
#include <hip/hip_runtime.h>
#include <hip/hip_bf16.h>

typedef __hip_bfloat16 bf16;
typedef __attribute__((ext_vector_type(8))) short short8;
typedef __attribute__((ext_vector_type(16))) float floatx16;

__device__ __forceinline__ float tof(bf16 x){ return __bfloat162float(x); }
__device__ __forceinline__ float bflo(unsigned u){ return __uint_as_float(u<<16); }
__device__ __forceinline__ float bfhi(unsigned u){ return __uint_as_float(u & 0xFFFF0000u); }
__device__ __forceinline__ float ldT(const void* p, long i, bool isf){
  return isf ? ((const float*)p)[i] : tof(((const bf16*)p)[i]);
}
__device__ __forceinline__ void stT(void* p, long i, bool isf, float v){
  if (isf) ((float*)p)[i] = v; else ((bf16*)p)[i] = __float2bfloat16(v);
}

#define LL 64
#define DD 144
#define NN 4096
#define HH 8
#define HDIM 18
#define SCALE 0.23570226039551584f
#define LOG2E 1.4426950408889634f

// ---- one-shot weight prep (also publishes dtype flag) ----
__global__ __launch_bounds__(256) void prep_weights(const unsigned* __restrict__ smaskw,
    int* __restrict__ dflag,
    const void* __restrict__ wqkv, const void* __restrict__ wg,
    const void* __restrict__ wout, const void* __restrict__ w1, const void* __restrict__ w2,
    const void* __restrict__ swq, const void* __restrict__ swkv,
    const void* __restrict__ swout, const void* __restrict__ sw1, const void* __restrict__ sw2,
    bf16* __restrict__ F1, bf16* __restrict__ Fout, bf16* __restrict__ Fw1,
    bf16* __restrict__ Fw2, bf16* __restrict__ Fs1, bf16* __restrict__ Wtswout,
    bf16* __restrict__ Wtst1, bf16* __restrict__ Wtst2){
  bool isf = (smaskw[0] == 0x3F800000u);
  if (blockIdx.x==0 && threadIdx.x==0) dflag[0] = isf ? 4 : 2;
  long t = (long)blockIdx.x*256 + threadIdx.x;
  if (t < 82944){
    int j=t&7, lane=(int)((t>>3)&63); long tk=t>>9; int ks=tk%9, tile=tk/9;
    int col=tile*32+(lane&31); int k=ks*16+(lane>>5)*8+j;
    float v = (col<432)? ldT(wqkv,(long)k*432+col,isf) : ldT(wg,(long)k*144+(col-432),isf);
    F1[t]=__float2bfloat16(v); return;
  } t -= 82944;
  if (t < 23040){
    int j=t&7, lane=(int)((t>>3)&63); long tk=t>>9; int ks=tk%9, tile=tk/9;
    int col=tile*32+(lane&31); if (col>143) col=143;
    int k=ks*16+(lane>>5)*8+j;
    Fout[t]=__float2bfloat16(ldT(wout,(long)k*144+col,isf)); return;
  } t -= 23040;
  if (t < 82944){
    int j=t&7, lane=(int)((t>>3)&63); long tk=t>>9; int ks=tk%9, tile=tk/9;
    int col=tile*32+(lane&31); int k=ks*16+(lane>>5)*8+j;
    Fw1[t]=__float2bfloat16(ldT(w1,(long)k*576+col,isf)); return;
  } t -= 82944;
  if (t < 92160){
    int j=t&7, lane=(int)((t>>3)&63); long tk=t>>9; int ks=tk%36, tile=tk/36;
    int col=tile*32+(lane&31); if (col>143) col=143;
    int k=ks*16+(lane>>5)*8+j;
    Fw2[t]=__float2bfloat16(ldT(w2,(long)k*144+col,isf)); return;
  } t -= 92160;
  if (t < 64512){
    int j=t&7, lane=(int)((t>>3)&63); long tk=t>>9; int ks=tk%9, tile=tk/9;
    int col=tile*32+(lane&31); if (col>431) col=431;
    int k=ks*16+(lane>>5)*8+j;
    float v = (col<144)? ldT(swq,(long)k*144+col,isf) : ldT(swkv,(long)k*288+(col-144),isf);
    Fs1[t]=__float2bfloat16(v); return;
  } t -= 64512;
  if (t < 20736){ int c=t/144,k=t-(long)c*144; Wtswout[t]=__float2bfloat16(ldT(swout,(long)k*144+c,isf)); return; }
  t -= 20736;
  if (t < 82944){ int c=t/144,k=t-(long)c*144; Wtst1[t]=__float2bfloat16(ldT(sw1,(long)k*576+c,isf)); return; }
  t -= 82944;
  if (t < 82944){ int c=t/576,k=t-(long)c*576; Wtst2[t]=__float2bfloat16(ldT(sw2,(long)k*144+c,isf)); return; }
}

// ---- LayerNorm rows -> bf16. 4 rows/block ----
__global__ __launch_bounds__(256) void ln_rows(const int* __restrict__ df,
    const void* __restrict__ xv,
    const void* __restrict__ gv, const void* __restrict__ bv,
    bf16* __restrict__ out){
  bool isf = (df[0]==4);
  int row = blockIdx.x*4 + (threadIdx.x>>6);
  int lane = threadIdx.x & 63;
  long base = (long)row*DD;
  float e0 = ldT(xv,base+lane,isf);
  float e1 = ldT(xv,base+lane+64,isf);
  float e2 = (lane<16) ? ldT(xv,base+lane+128,isf) : 0.f;
  float s = e0+e1+e2;
  #pragma unroll
  for (int o=32;o;o>>=1) s += __shfl_xor(s,o);
  float mean = s*(1.f/144.f);
  float d0=e0-mean, d1=e1-mean, d2=(lane<16)?(e2-mean):0.f;
  float v = d0*d0+d1*d1+d2*d2;
  #pragma unroll
  for (int o=32;o;o>>=1) v += __shfl_xor(v,o);
  float rstd = rsqrtf(v*(1.f/144.f)+1e-5f);
  out[base+lane]    = __float2bfloat16(d0*rstd*ldT(gv,lane,isf)    + ldT(bv,lane,isf));
  out[base+lane+64] = __float2bfloat16(d1*rstd*ldT(gv,lane+64,isf) + ldT(bv,lane+64,isf));
  if (lane<16)
    out[base+lane+128] = __float2bfloat16(d2*rstd*ldT(gv,lane+128,isf) + ldT(bv,lane+128,isf));
}

// ---- fused z @ [wqkv|wg] with frag weights. grid (9,64) ----
__global__ __launch_bounds__(256) void gemm_fused1(const int* __restrict__ df,
    const bf16* __restrict__ z, const bf16* __restrict__ F1,
    const void* __restrict__ pmask,
    bf16* __restrict__ Qb, bf16* __restrict__ Kf, bf16* __restrict__ Vf,
    bf16* __restrict__ gbuf){
  __shared__ short As[64*152];
  bool isf = df[0]==4;
  int row0 = blockIdx.y*64, col0 = blockIdx.x*64;
  int tid=threadIdx.x, lane=tid&63, l31=lane&31, w=tid>>6, wr=w>>1, wc=w&1;
  int g=(lane>>5)*8;
  for (int t=tid; t<64*72; t+=256){
    int m = t/72, dw = t%72;
    ((unsigned*)As)[m*76+dw] = ((const unsigned*)(z + (size_t)(row0+m)*144))[dw];
  }
  __syncthreads();
  int tile = blockIdx.x*2 + wc;
  const short8* wf = (const short8*)F1;
  floatx16 acc;
  #pragma unroll
  for (int i=0;i<16;i++) acc[i]=0.f;
  #pragma unroll
  for (int ks=0; ks<9; ks++){
    short8 af = *(const short8*)&As[(l31+32*wr)*152 + ks*16 + g];
    acc = __builtin_amdgcn_mfma_f32_32x32x16_bf16(af, wf[(tile*9+ks)*64+lane], acc, 0,0,0);
  }
  int col = col0 + wc*32 + l31;
  #pragma unroll
  for (int r=0;r<16;r++){
    int row = row0 + 32*wr + (r&3)+8*(r>>2)+4*(lane>>5);
    if (col < 144){
      int hh = col/18, d = col - hh*18;
      Qb[((size_t)hh*NN+row)*32 + d] = __float2bfloat16(acc[r]*(SCALE*LOG2E));
    } else if (col < 288){
      int c2 = col-144, hh = c2/18, d = c2 - hh*18;
      int f = d>>4, rem = d&15, gs = rem>>3, j = rem&7;
      Kf[((((size_t)hh*128 + (row>>5))*2 + f)*64 + gs*32 + (row&31))*8 + j]
        = __float2bfloat16(acc[r]);
    } else if (col < 432){
      int c2 = col-288, hh = c2/18, d = c2 - hh*18;
      float pm = (ldT(pmask,row,isf)>0.f)?1.f:0.f;
      int kin = row&31, f = kin>>4, k15 = kin&15;
      int gs = (k15>>2)&1, j = (k15&3) | (((k15>>3)&1)<<2);
      Vf[((((size_t)hh*128 + (row>>5))*2 + f)*64 + gs*32 + d)*8 + j]
        = __float2bfloat16(acc[r]*pm);
    } else {
      int c2 = col-432;
      float gt = 1.f/(1.f+__expf(fminf(-acc[r],30.f)));
      gbuf[(size_t)row*DD+c2] = __float2bfloat16(gt);
    }
  }
  if (blockIdx.x==0){
    for (int t=threadIdx.x; t<64*8*7; t+=256){
      int n = row0 + t/56; int rem = t%56; int hh = rem/7, dw = rem%7 + 9;
      ((unsigned*)(Qb + ((size_t)hh*NN+n)*32))[dw] = 0;
    }
    for (int t=threadIdx.x; t<64*8; t+=256){
      int n = row0 + (t>>3), hh = t&7;
      float pm = (ldT(pmask,n,isf)>0.f)?1.f:0.f;
      int kin = n&31, f = kin>>4, k15 = kin&15;
      int gs = (k15>>2)&1, j = (k15&3) | (((k15>>3)&1)<<2);
      Vf[((((size_t)hh*128 + (n>>5))*2 + f)*64 + gs*32 + 18)*8 + j] = __float2bfloat16(pm);
    }
  }
}

// ---- pair attention (round-16 winner): grid 1024, direct aob write ----
__global__ __launch_bounds__(256) void pair_attn_mfma(const int* __restrict__ df,
    const bf16* __restrict__ Qb, const bf16* __restrict__ Kf,
    const bf16* __restrict__ Vf, bf16* __restrict__ aob){
  __shared__ float Comb[4][32][20];
  int h = blockIdx.x >> 7, qt = blockIdx.x & 127;
  int tid = threadIdx.x;
  int w = tid >> 6, lane = tid & 63;
  int l31 = lane & 31, gsel = lane>>5;

  const unsigned* qp = (const unsigned*)(Qb + ((size_t)h*NN + qt*32 + l31)*32);
  short8 qf0, qf1;
  #pragma unroll
  for (int j=0;j<4;j++) ((unsigned*)&qf0)[j] = qp[gsel*4+j];
  #pragma unroll
  for (int j=0;j<4;j++) ((unsigned*)&qf1)[j] = qp[8+gsel*4+j];

  floatx16 o;
  #pragma unroll
  for (int i=0;i<16;i++) o[i]=0.f;

  const short8* kf8 = (const short8*)Kf + (size_t)h*16384;
  const short8* vf8 = (const short8*)Vf + (size_t)h*16384;
  int c0 = w*32;

  short8 af0 = kf8[(c0*2+0)*64 + lane];
  short8 af1 = kf8[(c0*2+1)*64 + lane];
  short8 av0 = vf8[(c0*2+0)*64 + lane];
  short8 av1 = vf8[(c0*2+1)*64 + lane];

  for (int cc=0; cc<32; cc++){
    int cn = c0 + (cc<31 ? cc+1 : 31);
    short8 naf0 = kf8[(cn*2+0)*64 + lane];
    short8 naf1 = kf8[(cn*2+1)*64 + lane];
    short8 nav0 = vf8[(cn*2+0)*64 + lane];
    short8 nav1 = vf8[(cn*2+1)*64 + lane];

    floatx16 s;
    #pragma unroll
    for (int i=0;i<16;i++) s[i]=0.f;
    s = __builtin_amdgcn_mfma_f32_32x32x16_bf16(af0, qf0, s, 0,0,0);
    s = __builtin_amdgcn_mfma_f32_32x32x16_bf16(af1, qf1, s, 0,0,0);

    short8 P1, P2;
    #pragma unroll
    for (int j=0;j<4;j++){
      unsigned e0 = __float_as_uint(__builtin_amdgcn_exp2f(s[2*j]));
      unsigned e1 = __float_as_uint(__builtin_amdgcn_exp2f(s[2*j+1]));
      ((unsigned*)&P1)[j] = (e0>>16) | (e1 & 0xFFFF0000u);
      unsigned e2 = __float_as_uint(__builtin_amdgcn_exp2f(s[8+2*j]));
      unsigned e3 = __float_as_uint(__builtin_amdgcn_exp2f(s[9+2*j]));
      ((unsigned*)&P2)[j] = (e2>>16) | (e3 & 0xFFFF0000u);
    }

    o = __builtin_amdgcn_mfma_f32_32x32x16_bf16(av0, P1, o, 0,0,0);
    o = __builtin_amdgcn_mfma_f32_32x32x16_bf16(av1, P2, o, 0,0,0);

    af0=naf0; af1=naf1; av0=nav0; av1=nav1;
  }

  #pragma unroll
  for (int r=0;r<16;r++){
    int d = (r&3) + 8*(r>>2) + 4*gsel;
    if (d < 20) Comb[w][l31][d] = o[r];
  }
  __syncthreads();
  for (int t=tid; t<32*HDIM; t+=256){
    int q = t/HDIM, d = t-q*HDIM;
    float num = Comb[0][q][d]+Comb[1][q][d]+Comb[2][q][d]+Comb[3][q][d];
    float den = Comb[0][q][18]+Comb[1][q][18]+Comb[2][q][18]+Comb[3][q][18];
    aob[(size_t)(qt*32+q)*DD + h*HDIM + d] = __float2bfloat16(num/fmaxf(den,1e-20f));
  }
}

// ---- pair tail (round-16 winner): 512 blocks x 8 rows, 512 threads, frag weights ----
__global__ __launch_bounds__(512) void pair_tail(const int* __restrict__ df,
    const bf16* __restrict__ aob, const bf16* __restrict__ gbuf,
    const void* __restrict__ pairv, const void* __restrict__ pmaskv,
    const bf16* __restrict__ Fout, const void* __restrict__ ptln_g, const void* __restrict__ ptln_b,
    const bf16* __restrict__ Fw1, const void* __restrict__ b1v,
    const bf16* __restrict__ Fw2, const void* __restrict__ b2v,
    const void* __restrict__ wb, void* __restrict__ outP, long outOff,
    float* __restrict__ biasb){
  __shared__ __align__(16) char smem[16384];
  float* p1  = (float*)smem;
  short* ts  = (short*)(smem + 4608);
  short* hh_ = (short*)(smem + 7040);
  float* outv = (float*)(smem + 7040);

  bool isf = df[0]==4;
  int tid=threadIdx.x, lane=tid&63, l31=lane&31, gsel=lane>>5, g=gsel*8;
  int w=tid>>6;
  int lrow = l31 & 7;
  int r0 = blockIdx.x*8;
  const short8* foutf = (const short8*)Fout;
  const short8* fw1f  = (const short8*)Fw1;
  const short8* fw2f  = (const short8*)Fw2;

  for (int t=tid; t<8*72; t+=512){
    int m=t/72, dw=t%72;
    ((unsigned*)ts)[m*76+dw] = ((const unsigned*)(aob + (size_t)(r0+m)*144))[dw];
  }
  __syncthreads();

  for (int tile=w; tile<5; tile+=8){
    int c0=tile*32;
    floatx16 acc;
    #pragma unroll
    for (int i=0;i<16;i++) acc[i]=0.f;
    #pragma unroll
    for (int ks=0; ks<9; ks++){
      short8 af = *(const short8*)&ts[lrow*152 + ks*16 + g];
      acc = __builtin_amdgcn_mfma_f32_32x32x16_bf16(af, foutf[(tile*9+ks)*64+lane], acc, 0,0,0);
    }
    if (c0+l31 < 144){
      #pragma unroll
      for (int r=0;r<16;r++){
        int row=(r&3)+8*(r>>2)+4*gsel;
        if (row<8) p1[row*144 + c0+l31] = acc[r];
      }
    }
  }
  __syncthreads();
  for (int t=tid; t<8*144; t+=512){
    int row=t/144; int col=t-row*144;
    long gidx=(long)(r0+row)*144 + col;
    float pm = (ldT(pmaskv, r0+row, isf)>0.f)?1.f:0.f;
    p1[t] = ldT(pairv,gidx,isf) + p1[t]*tof(gbuf[gidx])*pm;
  }
  __syncthreads();
  if (w < 8){
    int rr = w;
    float e0=p1[rr*144+lane], e1=p1[rr*144+lane+64], e2=(lane<16)?p1[rr*144+lane+128]:0.f;
    float s=e0+e1+e2;
    #pragma unroll
    for (int o=32;o;o>>=1) s += __shfl_xor(s,o);
    float mean=s*(1.f/144.f);
    float d0=e0-mean, d1=e1-mean, d2=(lane<16)?(e2-mean):0.f;
    float v=d0*d0+d1*d1+d2*d2;
    #pragma unroll
    for (int o=32;o;o>>=1) v += __shfl_xor(v,o);
    float rstd=rsqrtf(v*(1.f/144.f)+1e-5f);
    bf16 h0 = __float2bfloat16(d0*rstd*ldT(ptln_g,lane,isf)    + ldT(ptln_b,lane,isf));
    bf16 h1 = __float2bfloat16(d1*rstd*ldT(ptln_g,lane+64,isf) + ldT(ptln_b,lane+64,isf));
    ts[rr*152+lane]    = *reinterpret_cast<short*>(&h0);
    ts[rr*152+lane+64] = *reinterpret_cast<short*>(&h1);
    if (lane<16){
      bf16 h2 = __float2bfloat16(d2*rstd*ldT(ptln_g,lane+128,isf) + ldT(ptln_b,lane+128,isf));
      ts[rr*152+lane+128] = *reinterpret_cast<short*>(&h2);
    }
  }
  __syncthreads();
  for (int tile=w; tile<18; tile+=8){
    int c0=tile*32, colB=c0+l31;
    floatx16 acc;
    #pragma unroll
    for (int i=0;i<16;i++) acc[i]=0.f;
    #pragma unroll
    for (int ks=0; ks<9; ks++){
      short8 af = *(const short8*)&ts[lrow*152 + ks*16 + g];
      acc = __builtin_amdgcn_mfma_f32_32x32x16_bf16(af, fw1f[(tile*9+ks)*64+lane], acc, 0,0,0);
    }
    float bb = ldT(b1v,colB,isf);
    #pragma unroll
    for (int r=0;r<16;r++){
      int row=(r&3)+8*(r>>2)+4*gsel;
      if (row<8){
        bf16 hv = __float2bfloat16(fmaxf(acc[r]+bb,0.f));
        hh_[row*584 + colB] = *reinterpret_cast<short*>(&hv);
      }
    }
  }
  __syncthreads();
  floatx16 fin; int fc0 = -1;
  for (int tile=w; tile<5; tile+=8){
    int c0=tile*32;
    int colB=c0+l31; if (colB>143) colB=143;
    floatx16 acc;
    #pragma unroll
    for (int i=0;i<16;i++) acc[i]=0.f;
    #pragma unroll
    for (int ks=0; ks<36; ks++){
      short8 af = *(const short8*)&hh_[lrow*584 + ks*16 + g];
      acc = __builtin_amdgcn_mfma_f32_32x32x16_bf16(af, fw2f[(tile*36+ks)*64+lane], acc, 0,0,0);
    }
    float bb = ldT(b2v,colB,isf);
    #pragma unroll
    for (int r=0;r<16;r++){
      int row=(r&3)+8*(r>>2)+4*gsel;
      float val = 0.f;
      if (row<8){
        float pm = (ldT(pmaskv, r0+row, isf)>0.f)?1.f:0.f;
        val = p1[row*144 + colB] + (acc[r]+bb)*pm;
        if (c0+l31 < 144)
          stT(outP, outOff + (long)(r0+row)*144 + c0+l31, isf, val);
      }
      fin[r]=val;
    }
    fc0 = c0;
  }
  __syncthreads();
  if (fc0 >= 0 && fc0+l31 < 144){
    #pragma unroll
    for (int r=0;r<16;r++){
      int row=(r&3)+8*(r>>2)+4*gsel;
      if (row<8) outv[row*144 + fc0+l31] = fin[r];
    }
  }
  __syncthreads();
  {
    int n = tid>>3, hb = tid&7;
    if (n < 8){
      float acc=0.f;
      #pragma unroll 4
      for (int k=0;k<144;k++) acc += outv[n*144+k]*ldT(wb,k*8+hb,isf);
      biasb[(size_t)(r0+n)*8+hb]=acc;
    }
  }
}

// ---- fused LN(single) + zs @ [wq|wkv] with frag weights. grid (7,1) ----
__global__ __launch_bounds__(256) void gemm_s1(const int* __restrict__ df,
    const void* __restrict__ single, const void* __restrict__ g, const void* __restrict__ b,
    const bf16* __restrict__ Fs1,
    bf16* __restrict__ q_sb, bf16* __restrict__ kv_sb){
  __shared__ short As[64*152];
  bool isf = df[0]==4;
  int tid=threadIdx.x, lane=tid&63, l31=lane&31, w=tid>>6, wr=w>>1, wc=w&1;
  int gg=(lane>>5)*8;
  for (int rr=w; rr<64; rr+=4){
    long base=(long)rr*DD;
    float e0=ldT(single,base+lane,isf), e1=ldT(single,base+lane+64,isf);
    float e2=(lane<16)?ldT(single,base+lane+128,isf):0.f;
    float s=e0+e1+e2;
    #pragma unroll
    for (int o=32;o;o>>=1) s += __shfl_xor(s,o);
    float mean=s*(1.f/144.f);
    float d0=e0-mean, d1=e1-mean, d2=(lane<16)?(e2-mean):0.f;
    float v=d0*d0+d1*d1+d2*d2;
    #pragma unroll
    for (int o=32;o;o>>=1) v += __shfl_xor(v,o);
    float rstd=rsqrtf(v*(1.f/144.f)+1e-5f);
    bf16 h0=__float2bfloat16(d0*rstd*ldT(g,lane,isf)+ldT(b,lane,isf));
    bf16 h1=__float2bfloat16(d1*rstd*ldT(g,lane+64,isf)+ldT(b,lane+64,isf));
    As[rr*152+lane]=*reinterpret_cast<short*>(&h0);
    As[rr*152+lane+64]=*reinterpret_cast<short*>(&h1);
    if (lane<16){
      bf16 h2=__float2bfloat16(d2*rstd*ldT(g,lane+128,isf)+ldT(b,lane+128,isf));
      As[rr*152+lane+128]=*reinterpret_cast<short*>(&h2);
    }
  }
  __syncthreads();
  int tile = blockIdx.x*2 + wc;
  const short8* wf = (const short8*)Fs1;
  floatx16 acc;
  #pragma unroll
  for (int i=0;i<16;i++) acc[i]=0.f;
  #pragma unroll
  for (int ks=0; ks<9; ks++){
    short8 af = *(const short8*)&As[(l31+32*wr)*152 + ks*16 + gg];
    acc = __builtin_amdgcn_mfma_f32_32x32x16_bf16(af, wf[(tile*9+ks)*64+lane], acc, 0,0,0);
  }
  int col = tile*32 + l31;
  if (col < 432){
    #pragma unroll
    for (int r=0;r<16;r++){
      int row = 32*wr + (r&3)+8*(r>>2)+4*(lane>>5);
      if (col<144) q_sb[(size_t)row*DD+col] = __float2bfloat16(acc[r]);
      else kv_sb[(size_t)row*288+(col-144)] = __float2bfloat16(acc[r]);
    }
  }
}

// ---- fused single attention + tail. grid LL=64 blocks, 256 thr ----
__global__ __launch_bounds__(256) void single_tail(const int* __restrict__ df,
    const void* __restrict__ single, const bf16* __restrict__ q_sb,
    const bf16* __restrict__ kv_sb, const float* __restrict__ biasb,
    const void* __restrict__ smask, const bf16* __restrict__ Wtswout,
    const void* __restrict__ stln_g, const void* __restrict__ stln_b,
    const bf16* __restrict__ Wtst1, const void* __restrict__ st_b1,
    const bf16* __restrict__ Wtst2, const void* __restrict__ st_b2,
    void* __restrict__ outS){
  bool isf = df[0]==4;
  __shared__ short kvs[64*288];       // 36864 B
  __shared__ float pexp[8][64];       // 2048
  __shared__ float tot[8];
  __shared__ float bb[512];
  __shared__ float qs[DD], as_[DD], s1[DD], tss[DD], hs[576];
  int n = blockIdx.x, tid = threadIdx.x;
  // stage kv (all rows), q row n, bias slice, masks
  for (int t=tid; t<64*144; t+=256)
    ((unsigned*)kvs)[t] = ((const unsigned*)kv_sb)[t];
  if (tid<DD) qs[tid] = tof(q_sb[(size_t)n*DD+tid]);
  for (int t=tid; t<512; t+=256) bb[t] = biasb[(size_t)n*512 + t];
  __syncthreads();
  // attention: 512 (h,j) pairs over 256 threads
  #pragma unroll
  for (int pp=0; pp<2; pp++){
    int pi = tid + pp*256;
    int h = pi>>6, j = pi&63;
    const short* kr = &kvs[j*288 + h*HDIM];
    float s=0.f;
    #pragma unroll
    for (int d=0;d<HDIM;d++){
      unsigned u = ((unsigned)(unsigned short)kr[d])<<16;
      s += qs[h*HDIM+d]*__uint_as_float(u);
    }
    s = fminf(s*SCALE + bb[j*8+h], 30.f);
    pexp[h][j] = (ldT(smask,j,isf)>0.f) ? __expf(s) : 0.f;
  }
  __syncthreads();
  if (tid<8){
    float t2=0.f;
    #pragma unroll 4
    for (int j=0;j<64;j++) t2 += pexp[tid][j];
    tot[tid] = fmaxf(t2,1e-20f);
  }
  __syncthreads();
  if (tid<DD){
    int h = tid/HDIM, d = tid - h*HDIM;
    float acc=0.f;
    #pragma unroll 4
    for (int j=0;j<64;j++){
      unsigned u = ((unsigned)(unsigned short)kvs[j*288 + 144 + h*HDIM + d])<<16;
      acc += pexp[h][j]*__uint_as_float(u);
    }
    as_[tid] = acc/tot[h];
  }
  __syncthreads();
  // tail: wout + residual + LN + FFN + residual
  float sm = ldT(smask,n,isf);
  if (tid<DD){
    const unsigned* wr = (const unsigned*)(Wtswout + (size_t)tid*DD);
    float a=0.f;
    #pragma unroll 4
    for (int kw=0; kw<72; kw++){ unsigned u = wr[kw]; a += as_[2*kw]*bflo(u) + as_[2*kw+1]*bfhi(u); }
    s1[tid] = ldT(single,(long)n*DD+tid,isf) + a*sm;
  }
  __syncthreads();
  // LN stats (wave 0)
  __shared__ float mr[2];
  if (tid < 64){
    float e0 = s1[tid], e1 = s1[tid+64], e2 = (tid<16)?s1[tid+128]:0.f;
    float s = e0+e1+e2;
    #pragma unroll
    for (int o=32;o;o>>=1) s += __shfl_xor(s,o);
    float mean = s*(1.f/144.f);
    float d0=e0-mean, d1=e1-mean, d2=(tid<16)?(e2-mean):0.f;
    float v = d0*d0+d1*d1+d2*d2;
    #pragma unroll
    for (int o=32;o;o>>=1) v += __shfl_xor(v,o);
    if (tid==0){ mr[0]=mean; mr[1]=rsqrtf(v*(1.f/144.f)+1e-5f); }
  }
  __syncthreads();
  if (tid<DD) tss[tid] = (s1[tid]-mr[0])*mr[1]*ldT(stln_g,tid,isf) + ldT(stln_b,tid,isf);
  __syncthreads();
  for (int c=tid;c<576;c+=256){
    const unsigned* wr = (const unsigned*)(Wtst1 + (size_t)c*DD);
    float a=ldT(st_b1,c,isf);
    #pragma unroll 4
    for (int kw=0; kw<72; kw++){ unsigned u = wr[kw]; a += tss[2*kw]*bflo(u) + tss[2*kw+1]*bfhi(u); }
    hs[c]=fmaxf(a,0.f);
  }
  __syncthreads();
  if (tid<DD){
    const unsigned* wr = (const unsigned*)(Wtst2 + (size_t)tid*576);
    float a=ldT(st_b2,tid,isf);
    #pragma unroll 4
    for (int kw=0; kw<288; kw++){ unsigned u = wr[kw]; a += hs[2*kw]*bflo(u) + hs[2*kw+1]*bfhi(u); }
    stT(outS,(long)n*DD+tid,isf, s1[tid] + a*sm);
  }
}

extern "C" void kernel_launch(void* const* d_in, const int* in_sizes, int n_in,
                              void* d_out, int out_size, void* d_ws, size_t ws_size,
                              hipStream_t stream) {
  char* wsb = (char*)d_ws;
  int*   dflag = (int*)wsb;
  bf16*  F1     = (bf16*)(wsb + 16);
  bf16*  Fout   = F1 + 82944;
  bf16*  Fw1    = Fout + 23040;
  bf16*  Fw2    = Fw1 + 82944;
  bf16*  Fs1    = Fw2 + 92160;
  bf16*  Wtswout= Fs1 + 64512;
  bf16*  Wtst1  = Wtswout + 20736;
  bf16*  Wtst2  = Wtst1 + 82944;
  bf16*  Qb   = Wtst2 + 82944;
  bf16*  Kf   = Qb + (size_t)HH*NN*32;
  bf16*  Vf   = Kf + (size_t)HH*131072;
  bf16*  gbuf = Vf + (size_t)HH*131072;
  bf16*  z    = gbuf + (size_t)NN*DD;
  bf16*  aob  = z + (size_t)NN*DD;
  float* biasb= (float*)(aob + (size_t)NN*DD);
  bf16*  q_sb = (bf16*)(biasb + NN*8);
  bf16*  kv_sb= q_sb + LL*DD;

  const long OUTP_OFF = (long)LL*DD;

  prep_weights<<<2079,256,0,stream>>>((const unsigned*)d_in[2], dflag,
      d_in[6], d_in[7], d_in[8], d_in[11], d_in[13],
      d_in[17], d_in[18], d_in[20], d_in[23], d_in[25],
      F1, Fout, Fw1, Fw2, Fs1, Wtswout, Wtst1, Wtst2);

  // ---- pair path ----
  ln_rows<<<NN/4,256,0,stream>>>(dflag, d_in[1], d_in[4], d_in[5], z);
  gemm_fused1<<<dim3(9,64),256,0,stream>>>(dflag, z, F1, d_in[3], Qb, Kf, Vf, gbuf);
  pair_attn_mfma<<<1024,256,0,stream>>>(dflag, Qb, Kf, Vf, aob);
  pair_tail<<<512,512,0,stream>>>(dflag, aob, gbuf, d_in[1], d_in[3],
                                  Fout, d_in[9], d_in[10], Fw1, d_in[12],
                                  Fw2, d_in[14], d_in[19], d_out, OUTP_OFF, biasb);

  // ---- single path ----
  gemm_s1<<<dim3(7,1),256,0,stream>>>(dflag, d_in[0], d_in[15], d_in[16], Fs1, q_sb, kv_sb);
  single_tail<<<LL,256,0,stream>>>(dflag, d_in[0], q_sb, kv_sb, biasb, d_in[2],
                                   Wtswout, d_in[21], d_in[22], Wtst1, d_in[24],
                                   Wtst2, d_in[26], d_out);
  (void)in_sizes; (void)n_in; (void)out_size; (void)ws_size;
}